// Round 11
// baseline (133.653 us; speedup 1.0000x reference)
//
#include <hip/hip_runtime.h>
#include <hip/hip_bf16.h>

#define B 8
#define T 1024
#define E 128
#define H 8
#define DH 16
#define E3 384

typedef __attribute__((ext_vector_type(8))) short short8;
typedef __attribute__((ext_vector_type(4))) short short4s;
typedef __attribute__((ext_vector_type(4))) float f32x4;

// fp32 -> bf16 (round-to-nearest-even), bit pattern in a short
static __device__ inline short bf16s(float x) {
    union { float f; unsigned u; } v; v.f = x;
    unsigned r = v.u + 0x7fffu + ((v.u >> 16) & 1u);
    return (short)(r >> 16);
}

// exp2 via the HW transcendental (1 inst)
#if __has_builtin(__builtin_amdgcn_exp2f)
static __device__ inline float fexp2(float x) { return __builtin_amdgcn_exp2f(x); }
#else
static __device__ inline float fexp2(float x) { return __builtin_exp2f(x); }
#endif

// pack two fp32 into bf16x2 via v_cvt_pk_bf16_f32
static __device__ inline __hip_bfloat162 pk2(float a, float b) {
    float2 t; t.x = a; t.y = b;
    return __float22bfloat162_rn(t);
}

// async global->LDS, 16B per lane: LDS gets lane l's data at base + l*16
static __device__ inline void stage16(const void* g, void* l) {
    __builtin_amdgcn_global_load_lds(
        (const __attribute__((address_space(1))) void*)g,
        (__attribute__((address_space(3))) void*)l,
        16, 0, 0);
}

#define QSCALE 0.36067376022224085f   /* 0.25 * log2(e) */

// ---------------------------------------------------------------------------
// Kernel 1: pack win into bf16 K=256 complex-packed layout (precedes qkv).
// ---------------------------------------------------------------------------
__global__ void pack_win_kernel(
    const float* __restrict__ win_re, const float* __restrict__ win_im,
    short* __restrict__ Wp_re, short* __restrict__ Wp_im)
{
    int idx = blockIdx.x * 256 + threadIdx.x;   // [0, 384*128)
    int j = idx >> 7, e = idx & 127;
    float wr = win_re[idx], wi = win_im[idx];
    Wp_re[j*256 + e]       = bf16s(wr);
    Wp_re[j*256 + 128 + e] = bf16s(-wi);
    Wp_im[j*256 + e]       = bf16s(wi);
    Wp_im[j*256 + 128 + e] = bf16s(wr);
}

// ---------------------------------------------------------------------------
// Kernel 2: QKV projection, register-blocked over t + piggy-backed fuse
// (round-8 verified: W traffic /4, load:MFMA ratio /4).
//   blocks [0,512):   qkv (jg = bid&3, ttile = bid>>2)
//   blocks [512,576): Wfp fuse (idx = (bid-512)*256 + tid)
//   block  576:       fused bias (threads 0..127)
// ---------------------------------------------------------------------------
__global__ __launch_bounds__(256, 2) void qkv_fuse_kernel(
    const float* __restrict__ x_re, const float* __restrict__ x_im,
    const short* __restrict__ Wp_re, const short* __restrict__ Wp_im,
    const float* __restrict__ bin_re, const float* __restrict__ bin_im,
    const float* __restrict__ wout_re, const float* __restrict__ wout_im,
    const float* __restrict__ bout_re, const float* __restrict__ bout_im,
    const float* __restrict__ wt_re,   const float* __restrict__ wt_im,
    const float* __restrict__ bt_re,   const float* __restrict__ bt_im,
    short* __restrict__ Qpk, short* __restrict__ Kpk,
    short* __restrict__ Vtre, short* __restrict__ Vtim,
    short* __restrict__ Wfp_re, short* __restrict__ Wfp_im,
    float* __restrict__ bf_re, float* __restrict__ bf_im)
{
    __shared__ short8 xsh[4][8][64];   // 32 KB: [tsub][kt][lane]

    int bid = blockIdx.x;
    int tid = threadIdx.x;

    if (bid < 512) {
        // ---- qkv ----
        int wave = tid >> 6, lane = tid & 63;
        int col  = lane & 15, quad = lane >> 4;
        int jg    = bid & 3;           // j-group: 6 j-tiles
        int ttile = bid >> 2;          // [0,128): 64-t tile
        int b  = ttile >> 4;
        int t0 = (ttile & 15) * 64;

        // wave w builds t-subtile w's 8 kt-fragments, shares via LDS
        {
            int tglob = t0 + wave*16 + col;
            #pragma unroll
            for (int kt = 0; kt < 8; ++kt) {
                const float* xs = (kt < 4) ? x_re : x_im;
                const float* p = &xs[((long)(b*E + (kt & 3)*32 + quad*8))*T + tglob];
                float v0 = p[0], v1 = p[(long)T], v2 = p[2L*T], v3 = p[3L*T];
                float v4 = p[4L*T], v5 = p[5L*T], v6 = p[6L*T], v7 = p[7L*T];
                short8 xv;
                __hip_bfloat162* xp = (__hip_bfloat162*)&xv;
                xp[0] = pk2(v0, v1); xp[1] = pk2(v2, v3);
                xp[2] = pk2(v4, v5); xp[3] = pk2(v6, v7);
                xsh[wave][kt][lane] = xv;
            }
        }
        __syncthreads();

        // all 4 t-subtiles' fragments into registers (static indexing)
        short8 xr[4][8];
        #pragma unroll
        for (int ts = 0; ts < 4; ++ts)
            #pragma unroll
            for (int kt = 0; kt < 8; ++kt)
                xr[ts][kt] = xsh[ts][kt][lane];

        const f32x4 zero = {0.f,0.f,0.f,0.f};

        // 12 j-units (6 j-tiles x 2 halves) / 4 waves = 3 per wave
        for (int ui = 0; ui < 3; ++ui) {
            int idx  = wave * 3 + ui;          // [0,12)
            int half = idx >= 6;
            int u    = half ? idx - 6 : idx;
            int jt   = jg * 6 + u;             // [0,24): which*8 + h
            const short* Wsel = half ? Wp_im : Wp_re;
            const float* bias = half ? bin_im : bin_re;
            const short* wrow = &Wsel[(jt*16 + col)*256 + quad*8];

            f32x4 acc[4] = {zero, zero, zero, zero};
            #pragma unroll
            for (int kt = 0; kt < 8; ++kt) {
                short8 af = *(const short8*)(wrow + kt*32);
                #pragma unroll
                for (int ts = 0; ts < 4; ++ts)
                    acc[ts] = __builtin_amdgcn_mfma_f32_16x16x32_bf16(af, xr[ts][kt], acc[ts], 0, 0, 0);
            }

            int which = jt >> 3;               // 0 q, 1 k, 2 v
            int h = jt & 7;
            float scale = (which == 0) ? QSCALE : 1.0f;
            long bh = b*H + h;

            #pragma unroll
            for (int ts = 0; ts < 4; ++ts) {
                int tb = t0 + ts*16 + col;
                f32x4 res;
                #pragma unroll
                for (int r = 0; r < 4; ++r) {
                    int jgl = which*128 + h*16 + quad*4 + r;
                    res[r] = (acc[ts][r] + bias[jgl]) * scale;
                }
                if (which == 2) {
                    // V transposed + pi-interleaved: Vt[bh][dh][blk*32 + pos]
                    short* vt = half ? Vtim : Vtre;
                    int tloc = tb & 31, tblk = tb & ~31;
                    int u2 = tloc & 15;
                    int kk = (u2 >> 2)*8 + (u2 & 3) + ((tloc >= 16) ? 4 : 0);
                    #pragma unroll
                    for (int r = 0; r < 4; ++r)
                        vt[(bh*DH + quad*4 + r)*T + tblk + kk] = bf16s(res[r]);
                } else {
                    short* qk = (which == 0) ? Qpk : Kpk;
                    short4s pk;
                    __hip_bfloat162* pp = (__hip_bfloat162*)&pk;
                    pp[0] = pk2(res[0], res[1]);
                    pp[1] = pk2(res[2], res[3]);
                    *(short4s*)&qk[(bh*T + tb)*32 + half*16 + quad*4] = pk;
                }
            }
        }
    } else if (bid < 576) {
        // ---- fuse output linears: wf = wt @ wout (complex) ----
        int idx = (bid - 512) * 256 + tid;        // [0, E*E)
        int j = idx >> 7, e = idx & 127;
        float ar = 0.f, ai = 0.f;
        for (int m = 0; m < E; ++m) {
            float tr = wt_re[j*E+m], ti = wt_im[j*E+m];
            float pr = wout_re[m*E+e], pi = wout_im[m*E+e];
            ar += tr*pr - ti*pi;
            ai += tr*pi + ti*pr;
        }
        Wfp_re[j*256 + e]       = bf16s(ar);
        Wfp_re[j*256 + 128 + e] = bf16s(-ai);
        Wfp_im[j*256 + e]       = bf16s(ai);
        Wfp_im[j*256 + 128 + e] = bf16s(ar);
    } else {
        // ---- fused bias: bf = wt @ bout + bt ----
        if (tid < E) {
            float br = bt_re[tid], bi = bt_im[tid];
            for (int m = 0; m < E; ++m) {
                float tr = wt_re[tid*E+m], ti = wt_im[tid*E+m];
                br += tr*bout_re[m] - ti*bout_im[m];
                bi += tr*bout_im[m] + ti*bout_re[m];
            }
            bf_re[tid] = br; bf_im[tid] = bi;
        }
    }
}

// ---------------------------------------------------------------------------
// Kernel 3: MFMA flash attention, LDS-shared K/V, 2-tile windows, 4 q-tiles
// per wave. Round-11 change: grid 8x64 -> 4x64 (256 blocks); each wave now
// covers 64 queries (4 tiles A..D). Each head's 128KB K/V was streamed by 8
// blocks (64MB L2) -- now 4 (32MB), and each stage window hides under 2x
// compute. Occupancy 1 block/CU (4 waves): acceptable because the per-window
// compute (20 MFMA + 2x32 exp2/thread) far exceeds stage latency. VGPR ~110.
// Accumulator arrays indexed only by fully-unrolled compile-time indices.
// Per-output arithmetic/order/stores identical to the verified version.
// ---------------------------------------------------------------------------
__global__ __launch_bounds__(256, 2) void attn_mfma_kernel(
    const short* __restrict__ Qpk, const short* __restrict__ Kpk,
    const short* __restrict__ Vtre, const short* __restrict__ Vtim,
    short* __restrict__ Opk)
{
    __shared__ short lbuf[6][4][512];   // 24KB: [buf][component][1KB]

    int id   = blockIdx.x;              // [0, 256)
    int bh   = id & 63;
    int q0   = (id >> 6) * 256;         // 4 q-chunks of 256
    int tid  = threadIdx.x;
    int wave = tid >> 6;
    int lane = tid & 63;
    int col  = lane & 15;
    int quad = lane >> 4;

    long kq_base = (long)bh * T * 32;
    int qbase = q0 + wave * 64;         // this wave's 64 queries

    short8 qf[4];
    #pragma unroll
    for (int qi = 0; qi < 4; ++qi)
        qf[qi] = *(const short8*)&Qpk[kq_base + (long)(qbase + qi*16 + col)*32 + quad*8];

    // this wave's staging component: 0=kf0, 1=kf1, 2=vr, 3=vi
    const short* gsrc;
    int gstep;
    if (wave == 0)      { gsrc = &Kpk[kq_base + col*32 + quad*8];              gstep = 1024; }
    else if (wave == 1) { gsrc = &Kpk[kq_base + 512 + col*32 + quad*8];        gstep = 1024; }
    else if (wave == 2) { gsrc = &Vtre[(long)bh*DH*T + (long)col*T + quad*8];  gstep = 32; }
    else                { gsrc = &Vtim[(long)bh*DH*T + (long)col*T + quad*8];  gstep = 32; }

    short8 ones;
    #pragma unroll
    for (int i = 0; i < 8; ++i) ones[i] = (short)0x3F80;   // bf16 1.0

    const f32x4 zero = {0.f,0.f,0.f,0.f};
    f32x4 oR[4], oI[4], lS[4];
    #pragma unroll
    for (int qi = 0; qi < 4; ++qi) { oR[qi] = zero; oI[qi] = zero; lS[qi] = zero; }

    // one K/V tile worth of compute from LDS buffer bi
    auto COMPUTE = [&](int bi) {
        short8 kf0 = *(const short8*)&lbuf[bi][0][lane*8];
        short8 kf1 = *(const short8*)&lbuf[bi][1][lane*8];
        short8 vr  = *(const short8*)&lbuf[bi][2][lane*8];
        short8 vi  = *(const short8*)&lbuf[bi][3][lane*8];

        #pragma unroll
        for (int qi = 0; qi < 4; ++qi) {
            __builtin_amdgcn_s_setprio(1);
            f32x4 s0 = __builtin_amdgcn_mfma_f32_16x16x32_bf16(kf0, qf[qi], zero, 0, 0, 0);
            f32x4 s1 = __builtin_amdgcn_mfma_f32_16x16x32_bf16(kf1, qf[qi], zero, 0, 0, 0);
            __builtin_amdgcn_s_setprio(0);

            short8 pf;
            {
                __hip_bfloat162* pa = (__hip_bfloat162*)&pf;
                pa[0] = pk2(fexp2(s0[0]), fexp2(s0[1]));
                pa[1] = pk2(fexp2(s0[2]), fexp2(s0[3]));
                pa[2] = pk2(fexp2(s1[0]), fexp2(s1[1]));
                pa[3] = pk2(fexp2(s1[2]), fexp2(s1[3]));
            }

            __builtin_amdgcn_s_setprio(1);
            oR[qi] = __builtin_amdgcn_mfma_f32_16x16x32_bf16(vr, pf, oR[qi], 0, 0, 0);
            oI[qi] = __builtin_amdgcn_mfma_f32_16x16x32_bf16(vi, pf, oI[qi], 0, 0, 0);
            lS[qi] = __builtin_amdgcn_mfma_f32_16x16x32_bf16(ones, pf, lS[qi], 0, 0, 0);
            __builtin_amdgcn_s_setprio(0);
        }
    };

    // prologue: stage tiles 0..3 (distance-4 pipeline)
    stage16(gsrc, &lbuf[0][wave][0]); gsrc += gstep;
    stage16(gsrc, &lbuf[1][wave][0]); gsrc += gstep;
    stage16(gsrc, &lbuf[2][wave][0]); gsrc += gstep;
    stage16(gsrc, &lbuf[3][wave][0]); gsrc += gstep;
    asm volatile("s_waitcnt vmcnt(2)" ::: "memory");   // tiles 0,1 landed
    __builtin_amdgcn_s_barrier();
    __builtin_amdgcn_sched_barrier(0);

    for (int i = 0; i < 32; i += 2) {
        // stage tiles i+4, i+5 (stay in flight across this window's barrier)
        stage16(gsrc, &lbuf[(i+4)%6][wave][0]); gsrc += gstep;
        stage16(gsrc, &lbuf[(i+5)%6][wave][0]); gsrc += gstep;

        COMPUTE(i % 6);          // tile i
        COMPUTE((i+1) % 6);      // tile i+1

        // wait the OLDER two stages (tiles i+2,i+3); newest two in flight
        asm volatile("s_waitcnt vmcnt(2)" ::: "memory");
        __builtin_amdgcn_s_barrier();
        __builtin_amdgcn_sched_barrier(0);
    }

    // drain remaining LDS-DMA before epilogue/exit
    asm volatile("s_waitcnt vmcnt(0)" ::: "memory");

    int b = bh >> 3, h = bh & 7;

    #pragma unroll
    for (int qi = 0; qi < 4; ++qi) {
        float inv = 1.0f / lS[qi][0];
        long orow = ((long)(b*T + qbase + qi*16 + col))*256 + h*16 + quad*4;
        short4s pr, pi_;
        __hip_bfloat162* a = (__hip_bfloat162*)&pr;
        a[0] = pk2(oR[qi][0]*inv, oR[qi][1]*inv);
        a[1] = pk2(oR[qi][2]*inv, oR[qi][3]*inv);
        __hip_bfloat162* c = (__hip_bfloat162*)&pi_;
        c[0] = pk2(oI[qi][0]*inv, oI[qi][1]*inv);
        c[1] = pk2(oI[qi][2]*inv, oI[qi][3]*inv);
        *(short4s*)&Opk[orow]       = pr;
        *(short4s*)&Opk[orow + 128] = pi_;
    }
}

// ---------------------------------------------------------------------------
// Kernel 4: MFMA output projection, register-blocked over t (round-10
// verified): grid = 128 t-tiles (64t) x 4 j-groups; Opk staged once per
// block via global_load_lds; each wave owns ONE j-unit (8 af loads feed
// 32 MFMAs). W traffic 16MB; load:MFMA 1:4.
// ---------------------------------------------------------------------------
__global__ __launch_bounds__(256, 2) void outproj_mfma_kernel(
    const short* __restrict__ Opk,
    const short* __restrict__ Wfp_re, const short* __restrict__ Wfp_im,
    const float* __restrict__ bf_re, const float* __restrict__ bf_im,
    float* __restrict__ out)
{
    __shared__ short8 osh[4][8][64];   // 32 KB: [tsub][kt][lane]

    int tid  = threadIdx.x;
    int wave = tid >> 6, lane = tid & 63;
    int col  = lane & 15, quad = lane >> 4;
    int jg    = blockIdx.x & 3;        // j-group: 4 j-units
    int ttile = blockIdx.x >> 2;       // [0,128): 64-t tile
    int b  = ttile >> 4;
    int t0 = (ttile & 15) * 64;

    // wave w stages t-subtile w's 8 kt-fragments (async copy, no convert)
    {
        long trow = (long)b*T + t0 + wave*16 + col;
        #pragma unroll
        for (int kt = 0; kt < 8; ++kt)
            stage16(&Opk[trow*256 + kt*32 + quad*8], &osh[wave][kt][0]);
    }
    __syncthreads();   // vmcnt(0) drain + barrier: all 32 stages landed

    short8 xr[4][8];
    #pragma unroll
    for (int ts = 0; ts < 4; ++ts)
        #pragma unroll
        for (int kt = 0; kt < 8; ++kt)
            xr[ts][kt] = osh[ts][kt][lane];

    const f32x4 zero = {0.f,0.f,0.f,0.f};

    int nt = jg*4 + wave;              // [0,16): this wave's j-unit
    int is_im = nt >= 8;
    int jt = is_im ? nt - 8 : nt;      // [0,8)
    const short* Wsel = is_im ? Wfp_im : Wfp_re;
    const short* wrow = &Wsel[(jt*16 + col)*256 + quad*8];

    f32x4 acc[4] = {zero, zero, zero, zero};
    #pragma unroll
    for (int kt = 0; kt < 8; ++kt) {
        short8 af = *(const short8*)(wrow + kt*32);
        #pragma unroll
        for (int ts = 0; ts < 4; ++ts)
            acc[ts] = __builtin_amdgcn_mfma_f32_16x16x32_bf16(af, xr[ts][kt], acc[ts], 0, 0, 0);
    }

    const float* bias = is_im ? bf_im : bf_re;
    long part = is_im ? (long)B*E*T : 0;
    #pragma unroll
    for (int ts = 0; ts < 4; ++ts) {
        int tb = t0 + ts*16 + col;
        #pragma unroll
        for (int r = 0; r < 4; ++r) {
            int j = jt*16 + quad*4 + r;
            out[part + ((long)(b*E + j))*T + tb] = acc[ts][r] + bias[j];
        }
    }
}

// ---------------------------------------------------------------------------
extern "C" void kernel_launch(void* const* d_in, const int* in_sizes, int n_in,
                              void* d_out, int out_size, void* d_ws, size_t ws_size,
                              hipStream_t stream)
{
    const float* x_re    = (const float*)d_in[0];
    const float* x_im    = (const float*)d_in[1];
    const float* win_re  = (const float*)d_in[2];
    const float* win_im  = (const float*)d_in[3];
    const float* bin_re  = (const float*)d_in[4];
    const float* bin_im  = (const float*)d_in[5];
    const float* wout_re = (const float*)d_in[6];
    const float* wout_im = (const float*)d_in[7];
    const float* bout_re = (const float*)d_in[8];
    const float* bout_im = (const float*)d_in[9];
    const float* wt_re   = (const float*)d_in[10];
    const float* wt_im   = (const float*)d_in[11];
    const float* bt_re   = (const float*)d_in[12];
    const float* bt_im   = (const float*)d_in[13];
    float* out = (float*)d_out;

    // workspace layout (shorts/floats)
    short* Qpk  = (short*)d_ws;                       // 64*1024*32 = 2M shorts
    short* Kpk  = Qpk + (long)B*H*T*32;
    short* Vtre = Kpk + (long)B*H*T*32;               // 64*16*1024 = 1M shorts
    short* Vtim = Vtre + (long)B*H*DH*T;
    short* Opk  = Vtim + (long)B*H*DH*T;              // 8*1024*256 = 2M shorts
    short* Wp_re  = Opk + (long)B*T*256;
    short* Wp_im  = Wp_re + E3*256;
    short* Wfp_re = Wp_im + E3*256;
    short* Wfp_im = Wfp_re + E*256;
    float* bf_re  = (float*)(Wfp_im + E*256);
    float* bf_im  = bf_re + E;

    pack_win_kernel<<<dim3(E3*E/256), dim3(256), 0, stream>>>(
        win_re, win_im, Wp_re, Wp_im);

    qkv_fuse_kernel<<<dim3(577), dim3(256), 0, stream>>>(
        x_re, x_im, Wp_re, Wp_im, bin_re, bin_im,
        wout_re, wout_im, bout_re, bout_im,
        wt_re, wt_im, bt_re, bt_im,
        Qpk, Kpk, Vtre, Vtim,
        Wfp_re, Wfp_im, bf_re, bf_im);

    attn_mfma_kernel<<<dim3(4 * 64), dim3(256), 0, stream>>>(
        Qpk, Kpk, Vtre, Vtim, Opk);

    outproj_mfma_kernel<<<dim3(512), dim3(256), 0, stream>>>(
        Opk, Wfp_re, Wfp_im, bf_re, bf_im, out);
}

// Round 12
// 132.783 us; speedup vs baseline: 1.0066x; 1.0066x over previous
//
#include <hip/hip_runtime.h>
#include <hip/hip_bf16.h>

#define B 8
#define T 1024
#define E 128
#define H 8
#define DH 16
#define E3 384

typedef __attribute__((ext_vector_type(8))) short short8;
typedef __attribute__((ext_vector_type(4))) short short4s;
typedef __attribute__((ext_vector_type(4))) float f32x4;

// fp32 -> bf16 (round-to-nearest-even), bit pattern in a short
static __device__ inline short bf16s(float x) {
    union { float f; unsigned u; } v; v.f = x;
    unsigned r = v.u + 0x7fffu + ((v.u >> 16) & 1u);
    return (short)(r >> 16);
}

// exp2 via the HW transcendental (1 inst)
#if __has_builtin(__builtin_amdgcn_exp2f)
static __device__ inline float fexp2(float x) { return __builtin_amdgcn_exp2f(x); }
#else
static __device__ inline float fexp2(float x) { return __builtin_exp2f(x); }
#endif

// pack two fp32 into bf16x2 via v_cvt_pk_bf16_f32
static __device__ inline __hip_bfloat162 pk2(float a, float b) {
    float2 t; t.x = a; t.y = b;
    return __float22bfloat162_rn(t);
}

// async global->LDS, 16B per lane: LDS gets lane l's data at base + l*16
static __device__ inline void stage16(const void* g, void* l) {
    __builtin_amdgcn_global_load_lds(
        (const __attribute__((address_space(1))) void*)g,
        (__attribute__((address_space(3))) void*)l,
        16, 0, 0);
}

#define QSCALE 0.36067376022224085f   /* 0.25 * log2(e) */

// ---------------------------------------------------------------------------
// Kernel 1: pack win into bf16 K=256 complex-packed layout (precedes qkv).
// ---------------------------------------------------------------------------
__global__ void pack_win_kernel(
    const float* __restrict__ win_re, const float* __restrict__ win_im,
    short* __restrict__ Wp_re, short* __restrict__ Wp_im)
{
    int idx = blockIdx.x * 256 + threadIdx.x;   // [0, 384*128)
    int j = idx >> 7, e = idx & 127;
    float wr = win_re[idx], wi = win_im[idx];
    Wp_re[j*256 + e]       = bf16s(wr);
    Wp_re[j*256 + 128 + e] = bf16s(-wi);
    Wp_im[j*256 + e]       = bf16s(wi);
    Wp_im[j*256 + 128 + e] = bf16s(wr);
}

// ---------------------------------------------------------------------------
// Kernel 2: QKV projection, register-blocked over t + piggy-backed fuse
// (round-8 verified: W traffic /4, load:MFMA ratio /4).
//   blocks [0,512):   qkv (jg = bid&3, ttile = bid>>2)
//   blocks [512,576): Wfp fuse (idx = (bid-512)*256 + tid)
//   block  576:       fused bias (threads 0..127)
// ---------------------------------------------------------------------------
__global__ __launch_bounds__(256, 2) void qkv_fuse_kernel(
    const float* __restrict__ x_re, const float* __restrict__ x_im,
    const short* __restrict__ Wp_re, const short* __restrict__ Wp_im,
    const float* __restrict__ bin_re, const float* __restrict__ bin_im,
    const float* __restrict__ wout_re, const float* __restrict__ wout_im,
    const float* __restrict__ bout_re, const float* __restrict__ bout_im,
    const float* __restrict__ wt_re,   const float* __restrict__ wt_im,
    const float* __restrict__ bt_re,   const float* __restrict__ bt_im,
    short* __restrict__ Qpk, short* __restrict__ Kpk,
    short* __restrict__ Vtre, short* __restrict__ Vtim,
    short* __restrict__ Wfp_re, short* __restrict__ Wfp_im,
    float* __restrict__ bf_re, float* __restrict__ bf_im)
{
    __shared__ short8 xsh[4][8][64];   // 32 KB: [tsub][kt][lane]

    int bid = blockIdx.x;
    int tid = threadIdx.x;

    if (bid < 512) {
        // ---- qkv ----
        int wave = tid >> 6, lane = tid & 63;
        int col  = lane & 15, quad = lane >> 4;
        int jg    = bid & 3;           // j-group: 6 j-tiles
        int ttile = bid >> 2;          // [0,128): 64-t tile
        int b  = ttile >> 4;
        int t0 = (ttile & 15) * 64;

        // wave w builds t-subtile w's 8 kt-fragments, shares via LDS
        {
            int tglob = t0 + wave*16 + col;
            #pragma unroll
            for (int kt = 0; kt < 8; ++kt) {
                const float* xs = (kt < 4) ? x_re : x_im;
                const float* p = &xs[((long)(b*E + (kt & 3)*32 + quad*8))*T + tglob];
                float v0 = p[0], v1 = p[(long)T], v2 = p[2L*T], v3 = p[3L*T];
                float v4 = p[4L*T], v5 = p[5L*T], v6 = p[6L*T], v7 = p[7L*T];
                short8 xv;
                __hip_bfloat162* xp = (__hip_bfloat162*)&xv;
                xp[0] = pk2(v0, v1); xp[1] = pk2(v2, v3);
                xp[2] = pk2(v4, v5); xp[3] = pk2(v6, v7);
                xsh[wave][kt][lane] = xv;
            }
        }
        __syncthreads();

        // all 4 t-subtiles' fragments into registers (static indexing)
        short8 xr[4][8];
        #pragma unroll
        for (int ts = 0; ts < 4; ++ts)
            #pragma unroll
            for (int kt = 0; kt < 8; ++kt)
                xr[ts][kt] = xsh[ts][kt][lane];

        const f32x4 zero = {0.f,0.f,0.f,0.f};

        // 12 j-units (6 j-tiles x 2 halves) / 4 waves = 3 per wave
        for (int ui = 0; ui < 3; ++ui) {
            int idx  = wave * 3 + ui;          // [0,12)
            int half = idx >= 6;
            int u    = half ? idx - 6 : idx;
            int jt   = jg * 6 + u;             // [0,24): which*8 + h
            const short* Wsel = half ? Wp_im : Wp_re;
            const float* bias = half ? bin_im : bin_re;
            const short* wrow = &Wsel[(jt*16 + col)*256 + quad*8];

            f32x4 acc[4] = {zero, zero, zero, zero};
            #pragma unroll
            for (int kt = 0; kt < 8; ++kt) {
                short8 af = *(const short8*)(wrow + kt*32);
                #pragma unroll
                for (int ts = 0; ts < 4; ++ts)
                    acc[ts] = __builtin_amdgcn_mfma_f32_16x16x32_bf16(af, xr[ts][kt], acc[ts], 0, 0, 0);
            }

            int which = jt >> 3;               // 0 q, 1 k, 2 v
            int h = jt & 7;
            float scale = (which == 0) ? QSCALE : 1.0f;
            long bh = b*H + h;

            #pragma unroll
            for (int ts = 0; ts < 4; ++ts) {
                int tb = t0 + ts*16 + col;
                f32x4 res;
                #pragma unroll
                for (int r = 0; r < 4; ++r) {
                    int jgl = which*128 + h*16 + quad*4 + r;
                    res[r] = (acc[ts][r] + bias[jgl]) * scale;
                }
                if (which == 2) {
                    // V transposed + pi-interleaved: Vt[bh][dh][blk*32 + pos]
                    short* vt = half ? Vtim : Vtre;
                    int tloc = tb & 31, tblk = tb & ~31;
                    int u2 = tloc & 15;
                    int kk = (u2 >> 2)*8 + (u2 & 3) + ((tloc >= 16) ? 4 : 0);
                    #pragma unroll
                    for (int r = 0; r < 4; ++r)
                        vt[(bh*DH + quad*4 + r)*T + tblk + kk] = bf16s(res[r]);
                } else {
                    short* qk = (which == 0) ? Qpk : Kpk;
                    short4s pk;
                    __hip_bfloat162* pp = (__hip_bfloat162*)&pk;
                    pp[0] = pk2(res[0], res[1]);
                    pp[1] = pk2(res[2], res[3]);
                    *(short4s*)&qk[(bh*T + tb)*32 + half*16 + quad*4] = pk;
                }
            }
        }
    } else if (bid < 576) {
        // ---- fuse output linears: wf = wt @ wout (complex) ----
        int idx = (bid - 512) * 256 + tid;        // [0, E*E)
        int j = idx >> 7, e = idx & 127;
        float ar = 0.f, ai = 0.f;
        for (int m = 0; m < E; ++m) {
            float tr = wt_re[j*E+m], ti = wt_im[j*E+m];
            float pr = wout_re[m*E+e], pi = wout_im[m*E+e];
            ar += tr*pr - ti*pi;
            ai += tr*pi + ti*pr;
        }
        Wfp_re[j*256 + e]       = bf16s(ar);
        Wfp_re[j*256 + 128 + e] = bf16s(-ai);
        Wfp_im[j*256 + e]       = bf16s(ai);
        Wfp_im[j*256 + 128 + e] = bf16s(ar);
    } else {
        // ---- fused bias: bf = wt @ bout + bt ----
        if (tid < E) {
            float br = bt_re[tid], bi = bt_im[tid];
            for (int m = 0; m < E; ++m) {
                float tr = wt_re[tid*E+m], ti = wt_im[tid*E+m];
                br += tr*bout_re[m] - ti*bout_im[m];
                bi += tr*bout_im[m] + ti*bout_re[m];
            }
            bf_re[tid] = br; bf_im[tid] = bi;
        }
    }
}

// ---------------------------------------------------------------------------
// Kernel 3: MFMA flash attention, LDS-shared K/V, 2-tile barrier windows
// (round-10 verified optimum; round-11's 4-q-tile variant measured neutral-
// negative -- occupancy loss cancels traffic gain -- and was reverted).
// 6 buffers; per window stage tiles i+4,i+5, compute i,i+1, end with
// s_waitcnt vmcnt(2) + raw s_barrier. Final vmcnt(0) drain before exit.
// ---------------------------------------------------------------------------
__global__ __launch_bounds__(256, 2) void attn_mfma_kernel(
    const short* __restrict__ Qpk, const short* __restrict__ Kpk,
    const short* __restrict__ Vtre, const short* __restrict__ Vtim,
    short* __restrict__ Opk)
{
    __shared__ short lbuf[6][4][512];   // 24KB: [buf][component][1KB]

    int id   = blockIdx.x;
    int bh   = id & 63;
    int q0   = (id >> 6) * 128;
    int tid  = threadIdx.x;
    int wave = tid >> 6;
    int lane = tid & 63;
    int col  = lane & 15;
    int quad = lane >> 4;

    long kq_base = (long)bh * T * 32;
    int qbase = q0 + wave * 32;

    short8 qfA = *(const short8*)&Qpk[kq_base + (long)(qbase + col)*32 + quad*8];
    short8 qfB = *(const short8*)&Qpk[kq_base + (long)(qbase + 16 + col)*32 + quad*8];

    // this wave's staging component: 0=kf0, 1=kf1, 2=vr, 3=vi
    const short* gsrc;
    int gstep;
    if (wave == 0)      { gsrc = &Kpk[kq_base + col*32 + quad*8];              gstep = 1024; }
    else if (wave == 1) { gsrc = &Kpk[kq_base + 512 + col*32 + quad*8];        gstep = 1024; }
    else if (wave == 2) { gsrc = &Vtre[(long)bh*DH*T + (long)col*T + quad*8];  gstep = 32; }
    else                { gsrc = &Vtim[(long)bh*DH*T + (long)col*T + quad*8];  gstep = 32; }

    short8 ones;
    #pragma unroll
    for (int i = 0; i < 8; ++i) ones[i] = (short)0x3F80;   // bf16 1.0

    f32x4 oAr = {0,0,0,0}, oAi = {0,0,0,0}, lA = {0,0,0,0};
    f32x4 oBr = {0,0,0,0}, oBi = {0,0,0,0}, lB = {0,0,0,0};
    const f32x4 zero = {0.f,0.f,0.f,0.f};

    // one K/V tile worth of compute from LDS buffer bi
    auto COMPUTE = [&](int bi) {
        short8 kf0 = *(const short8*)&lbuf[bi][0][lane*8];
        short8 kf1 = *(const short8*)&lbuf[bi][1][lane*8];
        short8 vr  = *(const short8*)&lbuf[bi][2][lane*8];
        short8 vi  = *(const short8*)&lbuf[bi][3][lane*8];

        __builtin_amdgcn_s_setprio(1);
        f32x4 sA0 = __builtin_amdgcn_mfma_f32_16x16x32_bf16(kf0, qfA, zero, 0, 0, 0);
        f32x4 sA1 = __builtin_amdgcn_mfma_f32_16x16x32_bf16(kf1, qfA, zero, 0, 0, 0);
        f32x4 sB0 = __builtin_amdgcn_mfma_f32_16x16x32_bf16(kf0, qfB, zero, 0, 0, 0);
        f32x4 sB1 = __builtin_amdgcn_mfma_f32_16x16x32_bf16(kf1, qfB, zero, 0, 0, 0);
        __builtin_amdgcn_s_setprio(0);

        short8 pfA, pfB;
        {
            __hip_bfloat162* pa = (__hip_bfloat162*)&pfA;
            pa[0] = pk2(fexp2(sA0[0]), fexp2(sA0[1]));
            pa[1] = pk2(fexp2(sA0[2]), fexp2(sA0[3]));
            pa[2] = pk2(fexp2(sA1[0]), fexp2(sA1[1]));
            pa[3] = pk2(fexp2(sA1[2]), fexp2(sA1[3]));
            __hip_bfloat162* pb = (__hip_bfloat162*)&pfB;
            pb[0] = pk2(fexp2(sB0[0]), fexp2(sB0[1]));
            pb[1] = pk2(fexp2(sB0[2]), fexp2(sB0[3]));
            pb[2] = pk2(fexp2(sB1[0]), fexp2(sB1[1]));
            pb[3] = pk2(fexp2(sB1[2]), fexp2(sB1[3]));
        }

        __builtin_amdgcn_s_setprio(1);
        oAr = __builtin_amdgcn_mfma_f32_16x16x32_bf16(vr, pfA, oAr, 0, 0, 0);
        oAi = __builtin_amdgcn_mfma_f32_16x16x32_bf16(vi, pfA, oAi, 0, 0, 0);
        lA  = __builtin_amdgcn_mfma_f32_16x16x32_bf16(ones, pfA, lA, 0, 0, 0);
        oBr = __builtin_amdgcn_mfma_f32_16x16x32_bf16(vr, pfB, oBr, 0, 0, 0);
        oBi = __builtin_amdgcn_mfma_f32_16x16x32_bf16(vi, pfB, oBi, 0, 0, 0);
        lB  = __builtin_amdgcn_mfma_f32_16x16x32_bf16(ones, pfB, lB, 0, 0, 0);
        __builtin_amdgcn_s_setprio(0);
    };

    // prologue: stage tiles 0..3 (distance-4 pipeline)
    stage16(gsrc, &lbuf[0][wave][0]); gsrc += gstep;
    stage16(gsrc, &lbuf[1][wave][0]); gsrc += gstep;
    stage16(gsrc, &lbuf[2][wave][0]); gsrc += gstep;
    stage16(gsrc, &lbuf[3][wave][0]); gsrc += gstep;
    asm volatile("s_waitcnt vmcnt(2)" ::: "memory");   // tiles 0,1 landed
    __builtin_amdgcn_s_barrier();
    __builtin_amdgcn_sched_barrier(0);

    for (int i = 0; i < 32; i += 2) {
        // stage tiles i+4, i+5 (stay in flight across this window's barrier)
        stage16(gsrc, &lbuf[(i+4)%6][wave][0]); gsrc += gstep;
        stage16(gsrc, &lbuf[(i+5)%6][wave][0]); gsrc += gstep;

        COMPUTE(i % 6);          // tile i
        COMPUTE((i+1) % 6);      // tile i+1

        // wait the OLDER two stages (tiles i+2,i+3); newest two in flight
        asm volatile("s_waitcnt vmcnt(2)" ::: "memory");
        __builtin_amdgcn_s_barrier();
        __builtin_amdgcn_sched_barrier(0);
    }

    // drain remaining LDS-DMA before epilogue/exit (no stray writes after
    // this block's LDS slot is reallocated)
    asm volatile("s_waitcnt vmcnt(0)" ::: "memory");

    int b = bh >> 3, h = bh & 7;
    float invA = 1.0f / lA[0];
    float invB = 1.0f / lB[0];

    long orowA = ((long)(b*T + qbase + col))*256 + h*16 + quad*4;
    {
        short4s pr, pi_;
        __hip_bfloat162* a = (__hip_bfloat162*)&pr;
        a[0] = pk2(oAr[0]*invA, oAr[1]*invA);
        a[1] = pk2(oAr[2]*invA, oAr[3]*invA);
        __hip_bfloat162* c = (__hip_bfloat162*)&pi_;
        c[0] = pk2(oAi[0]*invA, oAi[1]*invA);
        c[1] = pk2(oAi[2]*invA, oAi[3]*invA);
        *(short4s*)&Opk[orowA]       = pr;
        *(short4s*)&Opk[orowA + 128] = pi_;
    }
    long orowB = orowA + 16L*256;
    {
        short4s pr, pi_;
        __hip_bfloat162* a = (__hip_bfloat162*)&pr;
        a[0] = pk2(oBr[0]*invB, oBr[1]*invB);
        a[1] = pk2(oBr[2]*invB, oBr[3]*invB);
        __hip_bfloat162* c = (__hip_bfloat162*)&pi_;
        c[0] = pk2(oBi[0]*invB, oBi[1]*invB);
        c[1] = pk2(oBi[2]*invB, oBi[3]*invB);
        *(short4s*)&Opk[orowB]       = pr;
        *(short4s*)&Opk[orowB + 128] = pi_;
    }
}

// ---------------------------------------------------------------------------
// Kernel 4: MFMA output projection, register-blocked over t (round-10
// verified): grid = 128 t-tiles (64t) x 4 j-groups; Opk staged once per
// block via global_load_lds; each wave owns ONE j-unit (8 af loads feed
// 32 MFMAs). W traffic 16MB; load:MFMA 1:4.
// ---------------------------------------------------------------------------
__global__ __launch_bounds__(256, 2) void outproj_mfma_kernel(
    const short* __restrict__ Opk,
    const short* __restrict__ Wfp_re, const short* __restrict__ Wfp_im,
    const float* __restrict__ bf_re, const float* __restrict__ bf_im,
    float* __restrict__ out)
{
    __shared__ short8 osh[4][8][64];   // 32 KB: [tsub][kt][lane]

    int tid  = threadIdx.x;
    int wave = tid >> 6, lane = tid & 63;
    int col  = lane & 15, quad = lane >> 4;
    int jg    = blockIdx.x & 3;        // j-group: 4 j-units
    int ttile = blockIdx.x >> 2;       // [0,128): 64-t tile
    int b  = ttile >> 4;
    int t0 = (ttile & 15) * 64;

    // wave w stages t-subtile w's 8 kt-fragments (async copy, no convert)
    {
        long trow = (long)b*T + t0 + wave*16 + col;
        #pragma unroll
        for (int kt = 0; kt < 8; ++kt)
            stage16(&Opk[trow*256 + kt*32 + quad*8], &osh[wave][kt][0]);
    }
    __syncthreads();   // vmcnt(0) drain + barrier: all 32 stages landed

    short8 xr[4][8];
    #pragma unroll
    for (int ts = 0; ts < 4; ++ts)
        #pragma unroll
        for (int kt = 0; kt < 8; ++kt)
            xr[ts][kt] = osh[ts][kt][lane];

    const f32x4 zero = {0.f,0.f,0.f,0.f};

    int nt = jg*4 + wave;              // [0,16): this wave's j-unit
    int is_im = nt >= 8;
    int jt = is_im ? nt - 8 : nt;      // [0,8)
    const short* Wsel = is_im ? Wfp_im : Wfp_re;
    const short* wrow = &Wsel[(jt*16 + col)*256 + quad*8];

    f32x4 acc[4] = {zero, zero, zero, zero};
    #pragma unroll
    for (int kt = 0; kt < 8; ++kt) {
        short8 af = *(const short8*)(wrow + kt*32);
        #pragma unroll
        for (int ts = 0; ts < 4; ++ts)
            acc[ts] = __builtin_amdgcn_mfma_f32_16x16x32_bf16(af, xr[ts][kt], acc[ts], 0, 0, 0);
    }

    const float* bias = is_im ? bf_im : bf_re;
    long part = is_im ? (long)B*E*T : 0;
    #pragma unroll
    for (int ts = 0; ts < 4; ++ts) {
        int tb = t0 + ts*16 + col;
        #pragma unroll
        for (int r = 0; r < 4; ++r) {
            int j = jt*16 + quad*4 + r;
            out[part + ((long)(b*E + j))*T + tb] = acc[ts][r] + bias[j];
        }
    }
}

// ---------------------------------------------------------------------------
extern "C" void kernel_launch(void* const* d_in, const int* in_sizes, int n_in,
                              void* d_out, int out_size, void* d_ws, size_t ws_size,
                              hipStream_t stream)
{
    const float* x_re    = (const float*)d_in[0];
    const float* x_im    = (const float*)d_in[1];
    const float* win_re  = (const float*)d_in[2];
    const float* win_im  = (const float*)d_in[3];
    const float* bin_re  = (const float*)d_in[4];
    const float* bin_im  = (const float*)d_in[5];
    const float* wout_re = (const float*)d_in[6];
    const float* wout_im = (const float*)d_in[7];
    const float* bout_re = (const float*)d_in[8];
    const float* bout_im = (const float*)d_in[9];
    const float* wt_re   = (const float*)d_in[10];
    const float* wt_im   = (const float*)d_in[11];
    const float* bt_re   = (const float*)d_in[12];
    const float* bt_im   = (const float*)d_in[13];
    float* out = (float*)d_out;

    // workspace layout (shorts/floats)
    short* Qpk  = (short*)d_ws;                       // 64*1024*32 = 2M shorts
    short* Kpk  = Qpk + (long)B*H*T*32;
    short* Vtre = Kpk + (long)B*H*T*32;               // 64*16*1024 = 1M shorts
    short* Vtim = Vtre + (long)B*H*DH*T;
    short* Opk  = Vtim + (long)B*H*DH*T;              // 8*1024*256 = 2M shorts
    short* Wp_re  = Opk + (long)B*T*256;
    short* Wp_im  = Wp_re + E3*256;
    short* Wfp_re = Wp_im + E3*256;
    short* Wfp_im = Wfp_re + E*256;
    float* bf_re  = (float*)(Wfp_im + E*256);
    float* bf_im  = bf_re + E;

    pack_win_kernel<<<dim3(E3*E/256), dim3(256), 0, stream>>>(
        win_re, win_im, Wp_re, Wp_im);

    qkv_fuse_kernel<<<dim3(577), dim3(256), 0, stream>>>(
        x_re, x_im, Wp_re, Wp_im, bin_re, bin_im,
        wout_re, wout_im, bout_re, bout_im,
        wt_re, wt_im, bt_re, bt_im,
        Qpk, Kpk, Vtre, Vtim,
        Wfp_re, Wfp_im, bf_re, bf_im);

    attn_mfma_kernel<<<dim3(8 * 64), dim3(256), 0, stream>>>(
        Qpk, Kpk, Vtre, Vtim, Opk);

    outproj_mfma_kernel<<<dim3(512), dim3(256), 0, stream>>>(
        Opk, Wfp_re, Wfp_im, bf_re, bf_im, out);
}